// Round 1
// baseline (3230.762 us; speedup 1.0000x reference)
//
#include <hip/hip_runtime.h>

// -------- graph preprocessing --------

__global__ void deg_init_kernel(float* __restrict__ deg, int n) {
    int i = blockIdx.x * blockDim.x + threadIdx.x;
    if (i < n) deg[i] = 1.0f;   // self-loop weight
}

__global__ void deg_edges_kernel(const int* __restrict__ dst, const float* __restrict__ ew,
                                 float* __restrict__ deg, int E) {
    int e = blockIdx.x * blockDim.x + threadIdx.x;
    if (e < E) atomicAdd(&deg[dst[e]], ew[e]);
}

__global__ void dinv_kernel(float* __restrict__ deg, int n) {
    int i = blockIdx.x * blockDim.x + threadIdx.x;
    if (i < n) deg[i] = rsqrtf(deg[i]);   // deg >= 1 always (self loop), in-place -> dinv
}

__global__ void norm_kernel(const int* __restrict__ src, const int* __restrict__ dst,
                            const float* __restrict__ ew, const float* __restrict__ dinv,
                            float* __restrict__ norm, int E) {
    int e = blockIdx.x * blockDim.x + threadIdx.x;
    if (e < E) norm[e] = dinv[src[e]] * ew[e] * dinv[dst[e]];
}

// -------- aggregation: agg = D^-1/2 (A+I) D^-1/2 h  (feature dim D) --------

// self-loop term, also fully initializes agg (clears poison)
template<int D>
__global__ void agg_init_kernel(const float* __restrict__ h, const float* __restrict__ dinv,
                                float* __restrict__ agg, int n) {
    int i = blockIdx.x * blockDim.x + threadIdx.x;   // over n*D elements
    if (i >= n * D) return;
    int node = i / D;
    float s = dinv[node];
    agg[i] = h[i] * (s * s);
}

template<int D>
__global__ void agg_edges_kernel(const int* __restrict__ src, const int* __restrict__ dst,
                                 const float* __restrict__ norm, const float* __restrict__ h,
                                 float* __restrict__ agg, int E) {
    int e = blockIdx.x * blockDim.x + threadIdx.x;
    if (e >= E) return;
    int s = src[e], d = dst[e];
    float w = norm[e];
    if constexpr (D >= 4) {
        const float4* hs = reinterpret_cast<const float4*>(h + (size_t)s * D);
        float* ad = agg + (size_t)d * D;
        #pragma unroll
        for (int q = 0; q < D / 4; ++q) {
            float4 v = hs[q];
            atomicAdd(ad + 4 * q + 0, v.x * w);
            atomicAdd(ad + 4 * q + 1, v.y * w);
            atomicAdd(ad + 4 * q + 2, v.z * w);
            atomicAdd(ad + 4 * q + 3, v.w * w);
        }
    } else {  // D == 2 (layer 1, raw x)
        float2 v = *reinterpret_cast<const float2*>(h + (size_t)s * 2);
        float* ad = agg + (size_t)d * 2;
        atomicAdd(ad + 0, v.x * w);
        atomicAdd(ad + 1, v.y * w);
    }
}

// -------- dense per-node matmul + ReLU: out = relu(agg @ W + b) --------

template<int DIN, int DOUT>
__global__ void linear_relu_kernel(const float* __restrict__ agg, const float* __restrict__ W,
                                   const float* __restrict__ b, float* __restrict__ out, int n) {
    int t = blockIdx.x * blockDim.x + threadIdx.x;   // over n*DOUT
    if (t >= n * DOUT) return;
    int i = t / DOUT, f = t % DOUT;
    float acc = b[f];
    const float* ai = agg + (size_t)i * DIN;
    #pragma unroll
    for (int k = 0; k < DIN; ++k)
        acc = fmaf(ai[k], W[k * DOUT + f], acc);
    out[t] = fmaxf(acc, 0.0f);
}

// -------- layer 3 matmul + ReLU fused with head: out = relu(agg@W3+b3) @ Wl + bl --------

__global__ void l3_head_kernel(const float* __restrict__ agg, const float* __restrict__ W3,
                               const float* __restrict__ b3, const float* __restrict__ Wl,
                               const float* __restrict__ bl, float* __restrict__ out, int n) {
    int i = blockIdx.x * blockDim.x + threadIdx.x;
    if (i >= n) return;
    float a[32];
    const float4* ap = reinterpret_cast<const float4*>(agg + (size_t)i * 32);
    #pragma unroll
    for (int q = 0; q < 8; ++q) {
        float4 v = ap[q];
        a[4 * q + 0] = v.x; a[4 * q + 1] = v.y; a[4 * q + 2] = v.z; a[4 * q + 3] = v.w;
    }
    float res = bl[0];
    for (int f = 0; f < 64; ++f) {       // W3/b3/Wl indices are lane-uniform -> scalar loads
        float acc = b3[f];
        #pragma unroll
        for (int k = 0; k < 32; ++k)
            acc = fmaf(a[k], W3[k * 64 + f], acc);
        res = fmaf(fmaxf(acc, 0.0f), Wl[f], res);
    }
    out[i] = res;
}

// -------- launch --------

static inline size_t align_up(size_t v, size_t a) { return (v + a - 1) & ~(a - 1); }

extern "C" void kernel_launch(void* const* d_in, const int* in_sizes, int n_in,
                              void* d_out, int out_size, void* d_ws, size_t ws_size,
                              hipStream_t stream) {
    const float* x  = (const float*)d_in[0];
    const int*   ei = (const int*)d_in[1];     // harness passes integer inputs as int32
    const float* ew = (const float*)d_in[2];
    const float* W1 = (const float*)d_in[3];
    const float* b1 = (const float*)d_in[4];
    const float* W2 = (const float*)d_in[5];
    const float* b2 = (const float*)d_in[6];
    const float* W3 = (const float*)d_in[7];
    const float* b3 = (const float*)d_in[8];
    const float* Wl = (const float*)d_in[9];
    const float* bl = (const float*)d_in[10];

    const int N = in_sizes[0] / 2;
    const int E = in_sizes[2];
    const int* src = ei;
    const int* dst = ei + E;

    char* ws = (char*)d_ws;
    size_t off = 0;
    float* dinv = (float*)(ws + off); off = align_up(off + (size_t)N * 4, 256);
    float* norm = (float*)(ws + off); off = align_up(off + (size_t)E * 4, 256);
    float* h1   = (float*)(ws + off); off = align_up(off + (size_t)N * 16 * 4, 256);
    float* h2   = (float*)(ws + off); off = align_up(off + (size_t)N * 32 * 4, 256);
    float* agg  = (float*)(ws + off); off = align_up(off + (size_t)N * 32 * 4, 256);

    const int B = 256;
    const int gN   = (N + B - 1) / B;
    const int gE   = (E + B - 1) / B;

    // graph preprocessing (shared across all 3 layers)
    deg_init_kernel<<<gN, B, 0, stream>>>(dinv, N);
    deg_edges_kernel<<<gE, B, 0, stream>>>(dst, ew, dinv, E);
    dinv_kernel<<<gN, B, 0, stream>>>(dinv, N);
    norm_kernel<<<gE, B, 0, stream>>>(src, dst, ew, dinv, norm, E);

    // layer 1: aggregate x (D=2), then 2->16 matmul + relu
    agg_init_kernel<2><<<(N * 2 + B - 1) / B, B, 0, stream>>>(x, dinv, agg, N);
    agg_edges_kernel<2><<<gE, B, 0, stream>>>(src, dst, norm, x, agg, E);
    linear_relu_kernel<2, 16><<<(N * 16 + B - 1) / B, B, 0, stream>>>(agg, W1, b1, h1, N);

    // layer 2: aggregate h1 (D=16), then 16->32 matmul + relu
    agg_init_kernel<16><<<(N * 16 + B - 1) / B, B, 0, stream>>>(h1, dinv, agg, N);
    agg_edges_kernel<16><<<gE, B, 0, stream>>>(src, dst, norm, h1, agg, E);
    linear_relu_kernel<16, 32><<<(N * 32 + B - 1) / B, B, 0, stream>>>(agg, W2, b2, h2, N);

    // layer 3: aggregate h2 (D=32), then fused 32->64 matmul + relu + head @Wl + bl
    agg_init_kernel<32><<<(N * 32 + B - 1) / B, B, 0, stream>>>(h2, dinv, agg, N);
    agg_edges_kernel<32><<<gE, B, 0, stream>>>(src, dst, norm, h2, agg, E);
    l3_head_kernel<<<gN, B, 0, stream>>>(agg, W3, b3, Wl, bl, (float*)d_out, N);
}

// Round 2
// 453.195 us; speedup vs baseline: 7.1289x; 7.1289x over previous
//
#include <hip/hip_runtime.h>

// ---------------- preprocessing: CSR build (dst-bucketed) ----------------

__global__ void init_kernel(float* __restrict__ deg, int* __restrict__ counts, int n) {
    int i = blockIdx.x * blockDim.x + threadIdx.x;
    if (i < n) { deg[i] = 1.0f; counts[i] = 0; }   // self-loop weight baked into deg
}

__global__ void count_deg_kernel(const int* __restrict__ dst, const float* __restrict__ ew,
                                 float* __restrict__ deg, int* __restrict__ counts, int E) {
    int e = blockIdx.x * blockDim.x + threadIdx.x;
    if (e >= E) return;
    int d = dst[e];
    atomicAdd(&deg[d], ew[e]);
    atomicAdd(&counts[d], 1);
}

// single-block exclusive scan of counts -> row_start & cursor; also deg -> dinv in-place
__global__ __launch_bounds__(1024) void scan_dinv_kernel(const int* __restrict__ counts,
                                                         float* __restrict__ dinv,
                                                         int* __restrict__ row_start,
                                                         int* __restrict__ cursor, int n) {
    __shared__ int sh[1024];
    int t = threadIdx.x;
    int CH = (n + 1023) >> 10;
    int lo = t * CH; if (lo > n) lo = n;
    int hi = lo + CH; if (hi > n) hi = n;
    int sum = 0;
    for (int i = lo; i < hi; ++i) sum += counts[i];
    sh[t] = sum;
    __syncthreads();
    #pragma unroll
    for (int off = 1; off < 1024; off <<= 1) {    // Hillis-Steele inclusive scan
        int add = (t >= off) ? sh[t - off] : 0;
        __syncthreads();
        sh[t] += add;
        __syncthreads();
    }
    int excl = sh[t] - sum;
    int run = excl;
    for (int i = lo; i < hi; ++i) {
        row_start[i] = run; cursor[i] = run;
        run += counts[i];
    }
    if (t == 1023) row_start[n] = run;            // == E
    for (int i = t; i < n; i += 1024) dinv[i] = rsqrtf(dinv[i]);   // deg >= 1 always
}

// scatter edges into dst buckets; payload = (src bits, norm) in one float2
__global__ void scatter_kernel(const int* __restrict__ src, const int* __restrict__ dst,
                               const float* __restrict__ ew, const float* __restrict__ dinv,
                               int* __restrict__ cursor, float2* __restrict__ epair, int E) {
    int e = blockIdx.x * blockDim.x + threadIdx.x;
    if (e >= E) return;
    int s = src[e], d = dst[e];
    float w = dinv[s] * ew[e] * dinv[d];
    int pos = atomicAdd(&cursor[d], 1);
    epair[pos] = make_float2(__int_as_float(s), w);
}

// ---------------- layer 1 fused: gather(D=2) + 2->16 matmul + relu ----------------

__global__ void layer1_kernel(const float2* __restrict__ x2, const float* __restrict__ dinv,
                              const float2* __restrict__ epair, const int* __restrict__ row_start,
                              const float* __restrict__ W1, const float* __restrict__ b1,
                              float* __restrict__ h1, int n) {
    int i = blockIdx.x * blockDim.x + threadIdx.x;
    if (i >= n) return;
    float s = dinv[i];
    float2 xv = x2[i];
    float ax = xv.x * s * s, ay = xv.y * s * s;
    int beg = row_start[i], end = row_start[i + 1];
    for (int e = beg; e < end; ++e) {
        float2 p = epair[e];
        float2 v = x2[__float_as_int(p.x)];
        ax = fmaf(p.y, v.x, ax);
        ay = fmaf(p.y, v.y, ay);
    }
    float4* o = reinterpret_cast<float4*>(h1 + (size_t)i * 16);
    #pragma unroll
    for (int q = 0; q < 4; ++q) {
        float4 v;
        v.x = fmaxf(fmaf(ax, W1[4 * q + 0], fmaf(ay, W1[16 + 4 * q + 0], b1[4 * q + 0])), 0.f);
        v.y = fmaxf(fmaf(ax, W1[4 * q + 1], fmaf(ay, W1[16 + 4 * q + 1], b1[4 * q + 1])), 0.f);
        v.z = fmaxf(fmaf(ax, W1[4 * q + 2], fmaf(ay, W1[16 + 4 * q + 2], b1[4 * q + 2])), 0.f);
        v.w = fmaxf(fmaf(ax, W1[4 * q + 3], fmaf(ay, W1[16 + 4 * q + 3], b1[4 * q + 3])), 0.f);
        o[q] = v;
    }
}

// ---------------- gather: agg[i,d] = dinv[i]^2 h[i,d] + sum_e norm_e h[src_e,d] ----------------

template<int D>
__global__ void gather_kernel(const float* __restrict__ h, const float* __restrict__ dinv,
                              const float2* __restrict__ epair, const int* __restrict__ row_start,
                              float* __restrict__ agg, int n) {
    int t = blockIdx.x * blockDim.x + threadIdx.x;
    int node = t / D, d = t % D;
    if (node >= n) return;
    float s = dinv[node];
    float acc = h[(size_t)node * D + d] * s * s;
    int beg = row_start[node], end = row_start[node + 1];
    for (int e = beg; e < end; ++e) {
        float2 p = epair[e];                       // broadcast across the D-lane group
        acc = fmaf(p.y, h[(size_t)__float_as_int(p.x) * D + d], acc);
    }
    agg[(size_t)node * D + d] = acc;
}

// ---------------- dense per-node matmul + ReLU ----------------

template<int DIN, int DOUT>
__global__ void linear_relu_kernel(const float* __restrict__ agg, const float* __restrict__ W,
                                   const float* __restrict__ b, float* __restrict__ out, int n) {
    int t = blockIdx.x * blockDim.x + threadIdx.x;
    if (t >= n * DOUT) return;
    int i = t / DOUT, f = t % DOUT;
    float acc = b[f];
    const float* ai = agg + (size_t)i * DIN;
    #pragma unroll
    for (int k = 0; k < DIN; ++k)
        acc = fmaf(ai[k], W[k * DOUT + f], acc);
    out[t] = fmaxf(acc, 0.0f);
}

// ---------------- layer 3 matmul + relu fused with head ----------------

__global__ void l3_head_kernel(const float* __restrict__ agg, const float* __restrict__ W3,
                               const float* __restrict__ b3, const float* __restrict__ Wl,
                               const float* __restrict__ bl, float* __restrict__ out, int n) {
    int i = blockIdx.x * blockDim.x + threadIdx.x;
    if (i >= n) return;
    float a[32];
    const float4* ap = reinterpret_cast<const float4*>(agg + (size_t)i * 32);
    #pragma unroll
    for (int q = 0; q < 8; ++q) {
        float4 v = ap[q];
        a[4 * q + 0] = v.x; a[4 * q + 1] = v.y; a[4 * q + 2] = v.z; a[4 * q + 3] = v.w;
    }
    float res = bl[0];
    for (int f = 0; f < 64; ++f) {                 // W3/b3/Wl lane-uniform -> scalar loads
        float acc = b3[f];
        #pragma unroll
        for (int k = 0; k < 32; ++k)
            acc = fmaf(a[k], W3[k * 64 + f], acc);
        res = fmaf(fmaxf(acc, 0.0f), Wl[f], res);
    }
    out[i] = res;
}

// ---------------- launch ----------------

static inline size_t align_up(size_t v, size_t a) { return (v + a - 1) & ~(a - 1); }

extern "C" void kernel_launch(void* const* d_in, const int* in_sizes, int n_in,
                              void* d_out, int out_size, void* d_ws, size_t ws_size,
                              hipStream_t stream) {
    const float* x  = (const float*)d_in[0];
    const int*   ei = (const int*)d_in[1];
    const float* ew = (const float*)d_in[2];
    const float* W1 = (const float*)d_in[3];
    const float* b1 = (const float*)d_in[4];
    const float* W2 = (const float*)d_in[5];
    const float* b2 = (const float*)d_in[6];
    const float* W3 = (const float*)d_in[7];
    const float* b3 = (const float*)d_in[8];
    const float* Wl = (const float*)d_in[9];
    const float* bl = (const float*)d_in[10];

    const int N = in_sizes[0] / 2;
    const int E = in_sizes[2];
    const int* src = ei;
    const int* dst = ei + E;

    char* ws = (char*)d_ws;
    size_t off = 0;
    float*  dinv      = (float*)(ws + off); off = align_up(off + (size_t)N * 4, 256);
    int*    counts    = (int*)(ws + off);   off = align_up(off + (size_t)N * 4, 256);
    int*    row_start = (int*)(ws + off);   off = align_up(off + (size_t)(N + 1) * 4, 256);
    int*    cursor    = (int*)(ws + off);   off = align_up(off + (size_t)N * 4, 256);
    float2* epair     = (float2*)(ws + off); off = align_up(off + (size_t)E * 8, 256);
    float*  h1        = (float*)(ws + off); off = align_up(off + (size_t)N * 16 * 4, 256);
    float*  h2        = (float*)(ws + off); off = align_up(off + (size_t)N * 32 * 4, 256);
    float*  agg       = (float*)(ws + off); off = align_up(off + (size_t)N * 32 * 4, 256);

    const int B = 256;
    const int gN = (N + B - 1) / B;
    const int gE = (E + B - 1) / B;

    // CSR build (shared across all 3 layers)
    init_kernel<<<gN, B, 0, stream>>>(dinv, counts, N);
    count_deg_kernel<<<gE, B, 0, stream>>>(dst, ew, dinv, counts, E);
    scan_dinv_kernel<<<1, 1024, 0, stream>>>(counts, dinv, row_start, cursor, N);
    scatter_kernel<<<gE, B, 0, stream>>>(src, dst, ew, dinv, cursor, epair, E);

    // layer 1: fused gather(D=2) + 2->16 matmul + relu
    layer1_kernel<<<gN, B, 0, stream>>>((const float2*)x, dinv, epair, row_start, W1, b1, h1, N);

    // layer 2: gather(D=16), 16->32 matmul + relu
    gather_kernel<16><<<(N * 16 + B - 1) / B, B, 0, stream>>>(h1, dinv, epair, row_start, agg, N);
    linear_relu_kernel<16, 32><<<(N * 32 + B - 1) / B, B, 0, stream>>>(agg, W2, b2, h2, N);

    // layer 3: gather(D=32), fused 32->64 matmul + relu + head
    gather_kernel<32><<<(N * 32 + B - 1) / B, B, 0, stream>>>(h2, dinv, epair, row_start, agg, N);
    l3_head_kernel<<<gN, B, 0, stream>>>(agg, W3, b3, Wl, bl, (float*)d_out, N);
}

// Round 3
// 336.529 us; speedup vs baseline: 9.6003x; 1.3467x over previous
//
#include <hip/hip_runtime.h>

// ---------------- preprocessing: CSR build (dst-bucketed) ----------------

__global__ void init_kernel(float* __restrict__ deg, int* __restrict__ counts, int n) {
    int i = blockIdx.x * blockDim.x + threadIdx.x;
    if (i < n) { deg[i] = 1.0f; counts[i] = 0; }   // self-loop weight baked into deg
}

__global__ void count_deg_kernel(const int* __restrict__ dst, const float* __restrict__ ew,
                                 float* __restrict__ deg, int* __restrict__ counts, int E) {
    int e = blockIdx.x * blockDim.x + threadIdx.x;
    if (e >= E) return;
    int d = dst[e];
    atomicAdd(&deg[d], ew[e]);
    atomicAdd(&counts[d], 1);
}

// ---- hierarchical scan: counts -> row_start/cursor (exclusive), deg -> dinv fused ----

constexpr int SCAN_T = 256;                    // threads per scan block
constexpr int SCAN_E = 8;                      // elements per thread (kernel 3)
constexpr int SCAN_ELEMS = SCAN_T * SCAN_E;    // 2048 elements per block

// kernel 1: per-block sum of counts; fused deg -> rsqrt(deg) in-place
__global__ __launch_bounds__(SCAN_T) void block_sum_dinv_kernel(
        const int* __restrict__ counts, float* __restrict__ dinv,
        int* __restrict__ bsum, int n) {
    __shared__ int sh[SCAN_T];
    int b = blockIdx.x, t = threadIdx.x;
    int base = b * SCAN_ELEMS;
    int lim = min(base + SCAN_ELEMS, n);
    int sum = 0;
    for (int i = base + t; i < lim; i += SCAN_T) {
        sum += counts[i];
        dinv[i] = rsqrtf(dinv[i]);             // deg >= 1 always (self loop)
    }
    sh[t] = sum;
    __syncthreads();
    #pragma unroll
    for (int off = SCAN_T / 2; off > 0; off >>= 1) {
        if (t < off) sh[t] += sh[t + off];
        __syncthreads();
    }
    if (t == 0) bsum[b] = sh[0];
}

// kernel 2: single small block scans the P block sums (P <= 256)
__global__ __launch_bounds__(256) void scan_bsums_kernel(const int* __restrict__ bsum,
                                                         int* __restrict__ boff, int P) {
    __shared__ int sh[256];
    int t = threadIdx.x;
    int v = (t < P) ? bsum[t] : 0;
    sh[t] = v;
    __syncthreads();
    #pragma unroll
    for (int off = 1; off < 256; off <<= 1) {
        int add = (t >= off) ? sh[t - off] : 0;
        __syncthreads();
        sh[t] += add;
        __syncthreads();
    }
    if (t < P) boff[t] = sh[t] - v;            // exclusive
}

// kernel 3: per-block exclusive scan of its 2048 counts, seeded with boff[b]
__global__ __launch_bounds__(SCAN_T) void scan_within_kernel(
        const int* __restrict__ counts, const int* __restrict__ boff,
        int* __restrict__ row_start, int* __restrict__ cursor, int n, int E) {
    __shared__ int sh[SCAN_T];
    int b = blockIdx.x, t = threadIdx.x;
    int base = b * SCAN_ELEMS + t * SCAN_E;
    int c[SCAN_E];
    #pragma unroll
    for (int k = 0; k < SCAN_E; ++k)
        c[k] = (base + k < n) ? counts[base + k] : 0;
    int sum = 0;
    #pragma unroll
    for (int k = 0; k < SCAN_E; ++k) sum += c[k];
    sh[t] = sum;
    __syncthreads();
    #pragma unroll
    for (int off = 1; off < SCAN_T; off <<= 1) {   // Hillis-Steele inclusive
        int add = (t >= off) ? sh[t - off] : 0;
        __syncthreads();
        sh[t] += add;
        __syncthreads();
    }
    int run = boff[b] + sh[t] - sum;               // exclusive prefix at this thread's first elem
    #pragma unroll
    for (int k = 0; k < SCAN_E; ++k) {
        int i = base + k;
        if (i < n) { row_start[i] = run; cursor[i] = run; }
        run += c[k];
    }
    if (b == 0 && t == 0) row_start[n] = E;
}

// scatter edges into dst buckets; payload = (src bits, norm) in one float2
__global__ void scatter_kernel(const int* __restrict__ src, const int* __restrict__ dst,
                               const float* __restrict__ ew, const float* __restrict__ dinv,
                               int* __restrict__ cursor, float2* __restrict__ epair, int E) {
    int e = blockIdx.x * blockDim.x + threadIdx.x;
    if (e >= E) return;
    int s = src[e], d = dst[e];
    float w = dinv[s] * ew[e] * dinv[d];
    int pos = atomicAdd(&cursor[d], 1);
    epair[pos] = make_float2(__int_as_float(s), w);
}

// ---------------- layer 1 fused: gather(D=2) + 2->16 matmul + relu ----------------

__global__ void layer1_kernel(const float2* __restrict__ x2, const float* __restrict__ dinv,
                              const float2* __restrict__ epair, const int* __restrict__ row_start,
                              const float* __restrict__ W1, const float* __restrict__ b1,
                              float* __restrict__ h1, int n) {
    int i = blockIdx.x * blockDim.x + threadIdx.x;
    if (i >= n) return;
    float s = dinv[i];
    float2 xv = x2[i];
    float ax = xv.x * s * s, ay = xv.y * s * s;
    int beg = row_start[i], end = row_start[i + 1];
    for (int e = beg; e < end; ++e) {
        float2 p = epair[e];
        float2 v = x2[__float_as_int(p.x)];
        ax = fmaf(p.y, v.x, ax);
        ay = fmaf(p.y, v.y, ay);
    }
    float4* o = reinterpret_cast<float4*>(h1 + (size_t)i * 16);
    #pragma unroll
    for (int q = 0; q < 4; ++q) {
        float4 v;
        v.x = fmaxf(fmaf(ax, W1[4 * q + 0], fmaf(ay, W1[16 + 4 * q + 0], b1[4 * q + 0])), 0.f);
        v.y = fmaxf(fmaf(ax, W1[4 * q + 1], fmaf(ay, W1[16 + 4 * q + 1], b1[4 * q + 1])), 0.f);
        v.z = fmaxf(fmaf(ax, W1[4 * q + 2], fmaf(ay, W1[16 + 4 * q + 2], b1[4 * q + 2])), 0.f);
        v.w = fmaxf(fmaf(ax, W1[4 * q + 3], fmaf(ay, W1[16 + 4 * q + 3], b1[4 * q + 3])), 0.f);
        o[q] = v;
    }
}

// ---------------- gather: agg[i,d] = dinv[i]^2 h[i,d] + sum_e norm_e h[src_e,d] ----------------

template<int D>
__global__ void gather_kernel(const float* __restrict__ h, const float* __restrict__ dinv,
                              const float2* __restrict__ epair, const int* __restrict__ row_start,
                              float* __restrict__ agg, int n) {
    int t = blockIdx.x * blockDim.x + threadIdx.x;
    int node = t / D, d = t % D;
    if (node >= n) return;
    float s = dinv[node];
    float acc = h[(size_t)node * D + d] * s * s;
    int beg = row_start[node], end = row_start[node + 1];
    for (int e = beg; e < end; ++e) {
        float2 p = epair[e];                       // broadcast across the D-lane group
        acc = fmaf(p.y, h[(size_t)__float_as_int(p.x) * D + d], acc);
    }
    agg[(size_t)node * D + d] = acc;
}

// ---------------- dense per-node matmul + ReLU ----------------

template<int DIN, int DOUT>
__global__ void linear_relu_kernel(const float* __restrict__ agg, const float* __restrict__ W,
                                   const float* __restrict__ b, float* __restrict__ out, int n) {
    int t = blockIdx.x * blockDim.x + threadIdx.x;
    if (t >= n * DOUT) return;
    int i = t / DOUT, f = t % DOUT;
    float acc = b[f];
    const float* ai = agg + (size_t)i * DIN;
    #pragma unroll
    for (int k = 0; k < DIN; ++k)
        acc = fmaf(ai[k], W[k * DOUT + f], acc);
    out[t] = fmaxf(acc, 0.0f);
}

// ---------------- layer 3 matmul + relu fused with head ----------------

__global__ void l3_head_kernel(const float* __restrict__ agg, const float* __restrict__ W3,
                               const float* __restrict__ b3, const float* __restrict__ Wl,
                               const float* __restrict__ bl, float* __restrict__ out, int n) {
    int i = blockIdx.x * blockDim.x + threadIdx.x;
    if (i >= n) return;
    float a[32];
    const float4* ap = reinterpret_cast<const float4*>(agg + (size_t)i * 32);
    #pragma unroll
    for (int q = 0; q < 8; ++q) {
        float4 v = ap[q];
        a[4 * q + 0] = v.x; a[4 * q + 1] = v.y; a[4 * q + 2] = v.z; a[4 * q + 3] = v.w;
    }
    float res = bl[0];
    for (int f = 0; f < 64; ++f) {                 // W3/b3/Wl lane-uniform -> scalar loads
        float acc = b3[f];
        #pragma unroll
        for (int k = 0; k < 32; ++k)
            acc = fmaf(a[k], W3[k * 64 + f], acc);
        res = fmaf(fmaxf(acc, 0.0f), Wl[f], res);
    }
    out[i] = res;
}

// ---------------- launch ----------------

static inline size_t align_up(size_t v, size_t a) { return (v + a - 1) & ~(a - 1); }

extern "C" void kernel_launch(void* const* d_in, const int* in_sizes, int n_in,
                              void* d_out, int out_size, void* d_ws, size_t ws_size,
                              hipStream_t stream) {
    const float* x  = (const float*)d_in[0];
    const int*   ei = (const int*)d_in[1];
    const float* ew = (const float*)d_in[2];
    const float* W1 = (const float*)d_in[3];
    const float* b1 = (const float*)d_in[4];
    const float* W2 = (const float*)d_in[5];
    const float* b2 = (const float*)d_in[6];
    const float* W3 = (const float*)d_in[7];
    const float* b3 = (const float*)d_in[8];
    const float* Wl = (const float*)d_in[9];
    const float* bl = (const float*)d_in[10];

    const int N = in_sizes[0] / 2;
    const int E = in_sizes[2];
    const int* src = ei;
    const int* dst = ei + E;

    char* ws = (char*)d_ws;
    size_t off = 0;
    float*  dinv      = (float*)(ws + off);  off = align_up(off + (size_t)N * 4, 256);
    int*    counts    = (int*)(ws + off);    off = align_up(off + (size_t)N * 4, 256);
    int*    row_start = (int*)(ws + off);    off = align_up(off + (size_t)(N + 1) * 4, 256);
    int*    cursor    = (int*)(ws + off);    off = align_up(off + (size_t)N * 4, 256);
    int*    bsum      = (int*)(ws + off);    off = align_up(off + 256 * 4, 256);
    int*    boff      = (int*)(ws + off);    off = align_up(off + 256 * 4, 256);
    float2* epair     = (float2*)(ws + off); off = align_up(off + (size_t)E * 8, 256);
    float*  h1        = (float*)(ws + off);  off = align_up(off + (size_t)N * 16 * 4, 256);
    float*  h2        = (float*)(ws + off);  off = align_up(off + (size_t)N * 32 * 4, 256);
    float*  agg       = (float*)(ws + off);  off = align_up(off + (size_t)N * 32 * 4, 256);

    const int B = 256;
    const int gN = (N + B - 1) / B;
    const int gE = (E + B - 1) / B;
    const int P  = (N + SCAN_ELEMS - 1) / SCAN_ELEMS;   // scan blocks (25 for N=50000)

    // CSR build (shared across all 3 layers)
    init_kernel<<<gN, B, 0, stream>>>(dinv, counts, N);
    count_deg_kernel<<<gE, B, 0, stream>>>(dst, ew, dinv, counts, E);
    block_sum_dinv_kernel<<<P, SCAN_T, 0, stream>>>(counts, dinv, bsum, N);
    scan_bsums_kernel<<<1, 256, 0, stream>>>(bsum, boff, P);
    scan_within_kernel<<<P, SCAN_T, 0, stream>>>(counts, boff, row_start, cursor, N, E);
    scatter_kernel<<<gE, B, 0, stream>>>(src, dst, ew, dinv, cursor, epair, E);

    // layer 1: fused gather(D=2) + 2->16 matmul + relu
    layer1_kernel<<<gN, B, 0, stream>>>((const float2*)x, dinv, epair, row_start, W1, b1, h1, N);

    // layer 2: gather(D=16), 16->32 matmul + relu
    gather_kernel<16><<<(N * 16 + B - 1) / B, B, 0, stream>>>(h1, dinv, epair, row_start, agg, N);
    linear_relu_kernel<16, 32><<<(N * 32 + B - 1) / B, B, 0, stream>>>(agg, W2, b2, h2, N);

    // layer 3: gather(D=32), fused 32->64 matmul + relu + head
    gather_kernel<32><<<(N * 32 + B - 1) / B, B, 0, stream>>>(h2, dinv, epair, row_start, agg, N);
    l3_head_kernel<<<gN, B, 0, stream>>>(agg, W3, b3, Wl, bl, (float*)d_out, N);
}

// Round 4
// 332.161 us; speedup vs baseline: 9.7265x; 1.0131x over previous
//
#include <hip/hip_runtime.h>

// ---------------- preprocessing: CSR build (dst-bucketed) ----------------

__global__ void init_kernel(float* __restrict__ deg, int* __restrict__ counts, int n) {
    int i = blockIdx.x * blockDim.x + threadIdx.x;
    if (i < n) { deg[i] = 1.0f; counts[i] = 0; }   // self-loop weight baked into deg
}

__global__ void count_deg_kernel(const int* __restrict__ dst, const float* __restrict__ ew,
                                 float* __restrict__ deg, int* __restrict__ counts, int E) {
    int e = blockIdx.x * blockDim.x + threadIdx.x;
    if (e >= E) return;
    int d = dst[e];
    atomicAdd(&deg[d], ew[e]);
    atomicAdd(&counts[d], 1);
}

// ---- hierarchical scan: counts -> row_start/cursor (exclusive), deg -> dinv fused ----

constexpr int SCAN_T = 256;                    // threads per scan block
constexpr int SCAN_E = 8;                      // elements per thread (kernel 3)
constexpr int SCAN_ELEMS = SCAN_T * SCAN_E;    // 2048 elements per block

// kernel 1: per-block sum of counts; fused deg -> rsqrt(deg) in-place
__global__ __launch_bounds__(SCAN_T) void block_sum_dinv_kernel(
        const int* __restrict__ counts, float* __restrict__ dinv,
        int* __restrict__ bsum, int n) {
    __shared__ int sh[SCAN_T];
    int b = blockIdx.x, t = threadIdx.x;
    int base = b * SCAN_ELEMS;
    int lim = min(base + SCAN_ELEMS, n);
    int sum = 0;
    for (int i = base + t; i < lim; i += SCAN_T) {
        sum += counts[i];
        dinv[i] = rsqrtf(dinv[i]);             // deg >= 1 always (self loop)
    }
    sh[t] = sum;
    __syncthreads();
    #pragma unroll
    for (int off = SCAN_T / 2; off > 0; off >>= 1) {
        if (t < off) sh[t] += sh[t + off];
        __syncthreads();
    }
    if (t == 0) bsum[b] = sh[0];
}

// kernel 2: single small block scans the P block sums (P <= 256)
__global__ __launch_bounds__(256) void scan_bsums_kernel(const int* __restrict__ bsum,
                                                         int* __restrict__ boff, int P) {
    __shared__ int sh[256];
    int t = threadIdx.x;
    int v = (t < P) ? bsum[t] : 0;
    sh[t] = v;
    __syncthreads();
    #pragma unroll
    for (int off = 1; off < 256; off <<= 1) {
        int add = (t >= off) ? sh[t - off] : 0;
        __syncthreads();
        sh[t] += add;
        __syncthreads();
    }
    if (t < P) boff[t] = sh[t] - v;            // exclusive
}

// kernel 3: per-block exclusive scan of its 2048 counts, seeded with boff[b]
__global__ __launch_bounds__(SCAN_T) void scan_within_kernel(
        const int* __restrict__ counts, const int* __restrict__ boff,
        int* __restrict__ row_start, int* __restrict__ cursor, int n, int E) {
    __shared__ int sh[SCAN_T];
    int b = blockIdx.x, t = threadIdx.x;
    int base = b * SCAN_ELEMS + t * SCAN_E;
    int c[SCAN_E];
    #pragma unroll
    for (int k = 0; k < SCAN_E; ++k)
        c[k] = (base + k < n) ? counts[base + k] : 0;
    int sum = 0;
    #pragma unroll
    for (int k = 0; k < SCAN_E; ++k) sum += c[k];
    sh[t] = sum;
    __syncthreads();
    #pragma unroll
    for (int off = 1; off < SCAN_T; off <<= 1) {   // Hillis-Steele inclusive
        int add = (t >= off) ? sh[t - off] : 0;
        __syncthreads();
        sh[t] += add;
        __syncthreads();
    }
    int run = boff[b] + sh[t] - sum;               // exclusive prefix at this thread's first elem
    #pragma unroll
    for (int k = 0; k < SCAN_E; ++k) {
        int i = base + k;
        if (i < n) { row_start[i] = run; cursor[i] = run; }
        run += c[k];
    }
    if (b == 0 && t == 0) row_start[n] = E;
}

// scatter edges into dst buckets; payload = (src bits, norm) in one float2
__global__ void scatter_kernel(const int* __restrict__ src, const int* __restrict__ dst,
                               const float* __restrict__ ew, const float* __restrict__ dinv,
                               int* __restrict__ cursor, float2* __restrict__ epair, int E) {
    int e = blockIdx.x * blockDim.x + threadIdx.x;
    if (e >= E) return;
    int s = src[e], d = dst[e];
    float w = dinv[s] * ew[e] * dinv[d];
    int pos = atomicAdd(&cursor[d], 1);
    epair[pos] = make_float2(__int_as_float(s), w);
}

// ---------------- layer 1 fused: gather(D=2) + 2->16 matmul + relu ----------------

__global__ void layer1_kernel(const float2* __restrict__ x2, const float* __restrict__ dinv,
                              const float2* __restrict__ epair, const int* __restrict__ row_start,
                              const float* __restrict__ W1, const float* __restrict__ b1,
                              float* __restrict__ h1, int n) {
    int i = blockIdx.x * blockDim.x + threadIdx.x;
    if (i >= n) return;
    float s = dinv[i];
    float2 xv = x2[i];
    float ax = xv.x * s * s, ay = xv.y * s * s;
    int beg = row_start[i], end = row_start[i + 1];
    for (int e = beg; e < end; ++e) {
        float2 p = epair[e];
        float2 v = x2[__float_as_int(p.x)];
        ax = fmaf(p.y, v.x, ax);
        ay = fmaf(p.y, v.y, ay);
    }
    float4* o = reinterpret_cast<float4*>(h1 + (size_t)i * 16);
    #pragma unroll
    for (int q = 0; q < 4; ++q) {
        float4 v;
        v.x = fmaxf(fmaf(ax, W1[4 * q + 0], fmaf(ay, W1[16 + 4 * q + 0], b1[4 * q + 0])), 0.f);
        v.y = fmaxf(fmaf(ax, W1[4 * q + 1], fmaf(ay, W1[16 + 4 * q + 1], b1[4 * q + 1])), 0.f);
        v.z = fmaxf(fmaf(ax, W1[4 * q + 2], fmaf(ay, W1[16 + 4 * q + 2], b1[4 * q + 2])), 0.f);
        v.w = fmaxf(fmaf(ax, W1[4 * q + 3], fmaf(ay, W1[16 + 4 * q + 3], b1[4 * q + 3])), 0.f);
        o[q] = v;
    }
}

// ---------------- gather: agg[i,d] = dinv[i]^2 h[i,d] + sum_e norm_e h[src_e,d] ----------------

template<int D>
__global__ void gather_kernel(const float* __restrict__ h, const float* __restrict__ dinv,
                              const float2* __restrict__ epair, const int* __restrict__ row_start,
                              float* __restrict__ agg, int n) {
    int t = blockIdx.x * blockDim.x + threadIdx.x;
    int node = t / D, d = t % D;
    if (node >= n) return;
    float s = dinv[node];
    float acc = h[(size_t)node * D + d] * s * s;
    int beg = row_start[node], end = row_start[node + 1];
    for (int e = beg; e < end; ++e) {
        float2 p = epair[e];                       // broadcast across the D-lane group
        acc = fmaf(p.y, h[(size_t)__float_as_int(p.x) * D + d], acc);
    }
    agg[(size_t)node * D + d] = acc;
}

// ---------------- dense per-node matmul + ReLU ----------------

template<int DIN, int DOUT>
__global__ void linear_relu_kernel(const float* __restrict__ agg, const float* __restrict__ W,
                                   const float* __restrict__ b, float* __restrict__ out, int n) {
    int t = blockIdx.x * blockDim.x + threadIdx.x;
    if (t >= n * DOUT) return;
    int i = t / DOUT, f = t % DOUT;
    float acc = b[f];
    const float* ai = agg + (size_t)i * DIN;
    #pragma unroll
    for (int k = 0; k < DIN; ++k)
        acc = fmaf(ai[k], W[k * DOUT + f], acc);
    out[t] = fmaxf(acc, 0.0f);
}

// ---------------- layer 3 matmul + relu fused with head ----------------

__global__ void l3_head_kernel(const float* __restrict__ agg, const float* __restrict__ W3,
                               const float* __restrict__ b3, const float* __restrict__ Wl,
                               const float* __restrict__ bl, float* __restrict__ out, int n) {
    int i = blockIdx.x * blockDim.x + threadIdx.x;
    if (i >= n) return;
    float a[32];
    const float4* ap = reinterpret_cast<const float4*>(agg + (size_t)i * 32);
    #pragma unroll
    for (int q = 0; q < 8; ++q) {
        float4 v = ap[q];
        a[4 * q + 0] = v.x; a[4 * q + 1] = v.y; a[4 * q + 2] = v.z; a[4 * q + 3] = v.w;
    }
    float res = bl[0];
    for (int f = 0; f < 64; ++f) {                 // W3/b3/Wl lane-uniform -> scalar loads
        float acc = b3[f];
        #pragma unroll
        for (int k = 0; k < 32; ++k)
            acc = fmaf(a[k], W3[k * 64 + f], acc);
        res = fmaf(fmaxf(acc, 0.0f), Wl[f], res);
    }
    out[i] = res;
}

// ---------------- launch ----------------

static inline size_t align_up(size_t v, size_t a) { return (v + a - 1) & ~(a - 1); }

extern "C" void kernel_launch(void* const* d_in, const int* in_sizes, int n_in,
                              void* d_out, int out_size, void* d_ws, size_t ws_size,
                              hipStream_t stream) {
    const float* x  = (const float*)d_in[0];
    const int*   ei = (const int*)d_in[1];
    const float* ew = (const float*)d_in[2];
    const float* W1 = (const float*)d_in[3];
    const float* b1 = (const float*)d_in[4];
    const float* W2 = (const float*)d_in[5];
    const float* b2 = (const float*)d_in[6];
    const float* W3 = (const float*)d_in[7];
    const float* b3 = (const float*)d_in[8];
    const float* Wl = (const float*)d_in[9];
    const float* bl = (const float*)d_in[10];

    const int N = in_sizes[0] / 2;
    const int E = in_sizes[2];
    const int* src = ei;
    const int* dst = ei + E;

    char* ws = (char*)d_ws;
    size_t off = 0;
    float*  dinv      = (float*)(ws + off);  off = align_up(off + (size_t)N * 4, 256);
    int*    counts    = (int*)(ws + off);    off = align_up(off + (size_t)N * 4, 256);
    int*    row_start = (int*)(ws + off);    off = align_up(off + (size_t)(N + 1) * 4, 256);
    int*    cursor    = (int*)(ws + off);    off = align_up(off + (size_t)N * 4, 256);
    int*    bsum      = (int*)(ws + off);    off = align_up(off + 256 * 4, 256);
    int*    boff      = (int*)(ws + off);    off = align_up(off + 256 * 4, 256);
    float2* epair     = (float2*)(ws + off); off = align_up(off + (size_t)E * 8, 256);
    float*  h1        = (float*)(ws + off);  off = align_up(off + (size_t)N * 16 * 4, 256);
    float*  h2        = (float*)(ws + off);  off = align_up(off + (size_t)N * 32 * 4, 256);
    float*  agg       = (float*)(ws + off);  off = align_up(off + (size_t)N * 32 * 4, 256);

    const int B = 256;
    const int gN = (N + B - 1) / B;
    const int gE = (E + B - 1) / B;
    const int P  = (N + SCAN_ELEMS - 1) / SCAN_ELEMS;   // scan blocks (25 for N=50000)

    // CSR build (shared across all 3 layers)
    init_kernel<<<gN, B, 0, stream>>>(dinv, counts, N);
    count_deg_kernel<<<gE, B, 0, stream>>>(dst, ew, dinv, counts, E);
    block_sum_dinv_kernel<<<P, SCAN_T, 0, stream>>>(counts, dinv, bsum, N);
    scan_bsums_kernel<<<1, 256, 0, stream>>>(bsum, boff, P);
    scan_within_kernel<<<P, SCAN_T, 0, stream>>>(counts, boff, row_start, cursor, N, E);
    scatter_kernel<<<gE, B, 0, stream>>>(src, dst, ew, dinv, cursor, epair, E);

    // layer 1: fused gather(D=2) + 2->16 matmul + relu
    layer1_kernel<<<gN, B, 0, stream>>>((const float2*)x, dinv, epair, row_start, W1, b1, h1, N);

    // layer 2: gather(D=16), 16->32 matmul + relu
    gather_kernel<16><<<(N * 16 + B - 1) / B, B, 0, stream>>>(h1, dinv, epair, row_start, agg, N);
    linear_relu_kernel<16, 32><<<(N * 32 + B - 1) / B, B, 0, stream>>>(agg, W2, b2, h2, N);

    // layer 3: gather(D=32), fused 32->64 matmul + relu + head
    gather_kernel<32><<<(N * 32 + B - 1) / B, B, 0, stream>>>(h2, dinv, epair, row_start, agg, N);
    l3_head_kernel<<<gN, B, 0, stream>>>(agg, W3, b3, Wl, bl, (float*)d_out, N);
}

// Round 5
// 243.462 us; speedup vs baseline: 13.2701x; 1.3643x over previous
//
#include <hip/hip_runtime.h>

// Fixed-point packing for the fused count+degree atomic:
//   low 40 bits  = sum of round(ew * 2^19)   (worst case 1.2M * 2^19 < 2^40)
//   high 24 bits = edge count                (max 16.7M edges)
constexpr float QSCALE = 524288.0f;            // 2^19
constexpr unsigned long long MASK40 = (1ull << 40) - 1;

// ---------------- preprocessing: CSR build (dst-bucketed, 1 atomic/edge) ----------------

__global__ void init_kernel(unsigned long long* __restrict__ cnt64, int n) {
    int i = blockIdx.x * blockDim.x + threadIdx.x;
    if (i < n) cnt64[i] = 0ull;
}

// one packed atomic per edge; return value's count field = rank within dst bucket
__global__ void count_deg_rank_kernel(const int* __restrict__ dst, const float* __restrict__ ew,
                                      unsigned long long* __restrict__ cnt64,
                                      int* __restrict__ rank, int E) {
    int base = blockIdx.x * 1024 + threadIdx.x;    // block covers 1024 consecutive edges
    #pragma unroll
    for (int k = 0; k < 4; ++k) {
        int e = base + k * 256;
        if (e < E) {
            int d = dst[e];
            unsigned int q = __float2uint_rn(ew[e] * QSCALE);
            unsigned long long inc = (1ull << 40) | (unsigned long long)q;
            unsigned long long old = atomicAdd(&cnt64[d], inc);
            rank[e] = (int)(old >> 40);
        }
    }
}

// ---- hierarchical scan: cnt64 -> row_start (exclusive); dinv = rsqrt(1 + qsum/2^19) fused ----

constexpr int SCAN_T = 256;
constexpr int SCAN_E = 8;
constexpr int SCAN_ELEMS = SCAN_T * SCAN_E;      // 2048 elements per block

__global__ __launch_bounds__(SCAN_T) void block_sum_dinv_kernel(
        const unsigned long long* __restrict__ cnt64, float* __restrict__ dinv,
        int* __restrict__ bsum, int n) {
    __shared__ int sh[SCAN_T];
    int b = blockIdx.x, t = threadIdx.x;
    int base = b * SCAN_ELEMS;
    int lim = min(base + SCAN_ELEMS, n);
    int sum = 0;
    for (int i = base + t; i < lim; i += SCAN_T) {
        unsigned long long v = cnt64[i];
        sum += (int)(v >> 40);
        dinv[i] = rsqrtf(1.0f + (float)(v & MASK40) * (1.0f / QSCALE));
    }
    sh[t] = sum;
    __syncthreads();
    #pragma unroll
    for (int off = SCAN_T / 2; off > 0; off >>= 1) {
        if (t < off) sh[t] += sh[t + off];
        __syncthreads();
    }
    if (t == 0) bsum[b] = sh[0];
}

__global__ __launch_bounds__(256) void scan_bsums_kernel(const int* __restrict__ bsum,
                                                         int* __restrict__ boff, int P) {
    __shared__ int sh[256];
    int t = threadIdx.x;
    int v = (t < P) ? bsum[t] : 0;
    sh[t] = v;
    __syncthreads();
    #pragma unroll
    for (int off = 1; off < 256; off <<= 1) {
        int add = (t >= off) ? sh[t - off] : 0;
        __syncthreads();
        sh[t] += add;
        __syncthreads();
    }
    if (t < P) boff[t] = sh[t] - v;              // exclusive
}

__global__ __launch_bounds__(SCAN_T) void scan_within_kernel(
        const unsigned long long* __restrict__ cnt64, const int* __restrict__ boff,
        int* __restrict__ row_start, int n, int E) {
    __shared__ int sh[SCAN_T];
    int b = blockIdx.x, t = threadIdx.x;
    int base = b * SCAN_ELEMS + t * SCAN_E;
    int c[SCAN_E];
    #pragma unroll
    for (int k = 0; k < SCAN_E; ++k)
        c[k] = (base + k < n) ? (int)(cnt64[base + k] >> 40) : 0;
    int sum = 0;
    #pragma unroll
    for (int k = 0; k < SCAN_E; ++k) sum += c[k];
    sh[t] = sum;
    __syncthreads();
    #pragma unroll
    for (int off = 1; off < SCAN_T; off <<= 1) {   // Hillis-Steele inclusive
        int add = (t >= off) ? sh[t - off] : 0;
        __syncthreads();
        sh[t] += add;
        __syncthreads();
    }
    int run = boff[b] + sh[t] - sum;
    #pragma unroll
    for (int k = 0; k < SCAN_E; ++k) {
        int i = base + k;
        if (i < n) row_start[i] = run;
        run += c[k];
    }
    if (b == 0 && t == 0) row_start[n] = E;
}

// atomic-free scatter: pos = row_start[dst] + rank; payload = (src bits, norm)
__global__ void scatter_kernel(const int* __restrict__ src, const int* __restrict__ dst,
                               const float* __restrict__ ew, const int* __restrict__ rank,
                               const float* __restrict__ dinv, const int* __restrict__ row_start,
                               float2* __restrict__ epair, int E) {
    int base = blockIdx.x * 1024 + threadIdx.x;
    #pragma unroll
    for (int k = 0; k < 4; ++k) {
        int e = base + k * 256;
        if (e < E) {
            int s = src[e], d = dst[e];
            float w = dinv[s] * ew[e] * dinv[d];
            epair[row_start[d] + rank[e]] = make_float2(__int_as_float(s), w);
        }
    }
}

// ---------------- layer 1 fused: gather(D=2) + 2->16 matmul + relu ----------------

__global__ void layer1_kernel(const float2* __restrict__ x2, const float* __restrict__ dinv,
                              const float2* __restrict__ epair, const int* __restrict__ row_start,
                              const float* __restrict__ W1, const float* __restrict__ b1,
                              float* __restrict__ h1, int n) {
    int i = blockIdx.x * blockDim.x + threadIdx.x;
    if (i >= n) return;
    float s = dinv[i];
    float2 xv = x2[i];
    float ax = xv.x * s * s, ay = xv.y * s * s;
    int beg = row_start[i], end = row_start[i + 1];
    for (int e = beg; e < end; ++e) {
        float2 p = epair[e];
        float2 v = x2[__float_as_int(p.x)];
        ax = fmaf(p.y, v.x, ax);
        ay = fmaf(p.y, v.y, ay);
    }
    float4* o = reinterpret_cast<float4*>(h1 + (size_t)i * 16);
    #pragma unroll
    for (int q = 0; q < 4; ++q) {
        float4 v;
        v.x = fmaxf(fmaf(ax, W1[4 * q + 0], fmaf(ay, W1[16 + 4 * q + 0], b1[4 * q + 0])), 0.f);
        v.y = fmaxf(fmaf(ax, W1[4 * q + 1], fmaf(ay, W1[16 + 4 * q + 1], b1[4 * q + 1])), 0.f);
        v.z = fmaxf(fmaf(ax, W1[4 * q + 2], fmaf(ay, W1[16 + 4 * q + 2], b1[4 * q + 2])), 0.f);
        v.w = fmaxf(fmaf(ax, W1[4 * q + 3], fmaf(ay, W1[16 + 4 * q + 3], b1[4 * q + 3])), 0.f);
        o[q] = v;
    }
}

// ---------------- gather: agg[i,d] = dinv[i]^2 h[i,d] + sum_e norm_e h[src_e,d] ----------------

template<int D>
__global__ void gather_kernel(const float* __restrict__ h, const float* __restrict__ dinv,
                              const float2* __restrict__ epair, const int* __restrict__ row_start,
                              float* __restrict__ agg, int n) {
    int t = blockIdx.x * blockDim.x + threadIdx.x;
    int node = t / D, d = t % D;
    if (node >= n) return;
    float s = dinv[node];
    float acc = h[(size_t)node * D + d] * s * s;
    int beg = row_start[node], end = row_start[node + 1];
    for (int e = beg; e < end; ++e) {
        float2 p = epair[e];                       // broadcast across the D-lane group
        acc = fmaf(p.y, h[(size_t)__float_as_int(p.x) * D + d], acc);
    }
    agg[(size_t)node * D + d] = acc;
}

// ---------------- dense per-node matmul + ReLU ----------------

template<int DIN, int DOUT>
__global__ void linear_relu_kernel(const float* __restrict__ agg, const float* __restrict__ W,
                                   const float* __restrict__ b, float* __restrict__ out, int n) {
    int t = blockIdx.x * blockDim.x + threadIdx.x;
    if (t >= n * DOUT) return;
    int i = t / DOUT, f = t % DOUT;
    float acc = b[f];
    const float* ai = agg + (size_t)i * DIN;
    #pragma unroll
    for (int k = 0; k < DIN; ++k)
        acc = fmaf(ai[k], W[k * DOUT + f], acc);
    out[t] = fmaxf(acc, 0.0f);
}

// ---------------- layer 3 matmul + relu fused with head ----------------

__global__ void l3_head_kernel(const float* __restrict__ agg, const float* __restrict__ W3,
                               const float* __restrict__ b3, const float* __restrict__ Wl,
                               const float* __restrict__ bl, float* __restrict__ out, int n) {
    int i = blockIdx.x * blockDim.x + threadIdx.x;
    if (i >= n) return;
    float a[32];
    const float4* ap = reinterpret_cast<const float4*>(agg + (size_t)i * 32);
    #pragma unroll
    for (int q = 0; q < 8; ++q) {
        float4 v = ap[q];
        a[4 * q + 0] = v.x; a[4 * q + 1] = v.y; a[4 * q + 2] = v.z; a[4 * q + 3] = v.w;
    }
    float res = bl[0];
    for (int f = 0; f < 64; ++f) {                 // W3/b3/Wl lane-uniform -> scalar loads
        float acc = b3[f];
        #pragma unroll
        for (int k = 0; k < 32; ++k)
            acc = fmaf(a[k], W3[k * 64 + f], acc);
        res = fmaf(fmaxf(acc, 0.0f), Wl[f], res);
    }
    out[i] = res;
}

// ---------------- launch ----------------

static inline size_t align_up(size_t v, size_t a) { return (v + a - 1) & ~(a - 1); }

extern "C" void kernel_launch(void* const* d_in, const int* in_sizes, int n_in,
                              void* d_out, int out_size, void* d_ws, size_t ws_size,
                              hipStream_t stream) {
    const float* x  = (const float*)d_in[0];
    const int*   ei = (const int*)d_in[1];
    const float* ew = (const float*)d_in[2];
    const float* W1 = (const float*)d_in[3];
    const float* b1 = (const float*)d_in[4];
    const float* W2 = (const float*)d_in[5];
    const float* b2 = (const float*)d_in[6];
    const float* W3 = (const float*)d_in[7];
    const float* b3 = (const float*)d_in[8];
    const float* Wl = (const float*)d_in[9];
    const float* bl = (const float*)d_in[10];

    const int N = in_sizes[0] / 2;
    const int E = in_sizes[2];
    const int* src = ei;
    const int* dst = ei + E;

    char* ws = (char*)d_ws;
    size_t off = 0;
    unsigned long long* cnt64 = (unsigned long long*)(ws + off); off = align_up(off + (size_t)N * 8, 256);
    float*  dinv      = (float*)(ws + off);  off = align_up(off + (size_t)N * 4, 256);
    int*    row_start = (int*)(ws + off);    off = align_up(off + (size_t)(N + 1) * 4, 256);
    int*    rank      = (int*)(ws + off);    off = align_up(off + (size_t)E * 4, 256);
    int*    bsum      = (int*)(ws + off);    off = align_up(off + 256 * 4, 256);
    int*    boff      = (int*)(ws + off);    off = align_up(off + 256 * 4, 256);
    float2* epair     = (float2*)(ws + off); off = align_up(off + (size_t)E * 8, 256);
    float*  h1        = (float*)(ws + off);  off = align_up(off + (size_t)N * 16 * 4, 256);
    float*  h2        = (float*)(ws + off);  off = align_up(off + (size_t)N * 32 * 4, 256);
    float*  agg       = (float*)(ws + off);  off = align_up(off + (size_t)N * 32 * 4, 256);

    const int B = 256;
    const int gN = (N + B - 1) / B;
    const int gE4 = (E + 1023) / 1024;                 // 4 edges per thread
    const int P  = (N + SCAN_ELEMS - 1) / SCAN_ELEMS;  // 25 scan blocks for N=50000

    // CSR build (shared across all 3 layers) — exactly 1 atomic per edge total
    init_kernel<<<gN, B, 0, stream>>>(cnt64, N);
    count_deg_rank_kernel<<<gE4, B, 0, stream>>>(dst, ew, cnt64, rank, E);
    block_sum_dinv_kernel<<<P, SCAN_T, 0, stream>>>(cnt64, dinv, bsum, N);
    scan_bsums_kernel<<<1, 256, 0, stream>>>(bsum, boff, P);
    scan_within_kernel<<<P, SCAN_T, 0, stream>>>(cnt64, boff, row_start, N, E);
    scatter_kernel<<<gE4, B, 0, stream>>>(src, dst, ew, rank, dinv, row_start, epair, E);

    // layer 1: fused gather(D=2) + 2->16 matmul + relu
    layer1_kernel<<<gN, B, 0, stream>>>((const float2*)x, dinv, epair, row_start, W1, b1, h1, N);

    // layer 2: gather(D=16), 16->32 matmul + relu
    gather_kernel<16><<<(N * 16 + B - 1) / B, B, 0, stream>>>(h1, dinv, epair, row_start, agg, N);
    linear_relu_kernel<16, 32><<<(N * 32 + B - 1) / B, B, 0, stream>>>(agg, W2, b2, h2, N);

    // layer 3: gather(D=32), fused 32->64 matmul + relu + head
    gather_kernel<32><<<(N * 32 + B - 1) / B, B, 0, stream>>>(h2, dinv, epair, row_start, agg, N);
    l3_head_kernel<<<gN, B, 0, stream>>>(agg, W3, b3, Wl, bl, (float*)d_out, N);
}

// Round 6
// 218.197 us; speedup vs baseline: 14.8067x; 1.1158x over previous
//
#include <hip/hip_runtime.h>

// Fixed-point packing for the fused count+degree atomic:
//   low 40 bits  = sum of round(ew * 2^19)   (worst case 1.2M * 2^19 < 2^40)
//   high 24 bits = edge count                (max 16.7M edges)
constexpr float QSCALE = 524288.0f;            // 2^19
constexpr unsigned long long MASK40 = (1ull << 40) - 1;

// ---------------- preprocessing: CSR build (dst-bucketed, 1 atomic/edge) ----------------

__global__ void init_kernel(unsigned long long* __restrict__ cnt64, int n) {
    int i = blockIdx.x * blockDim.x + threadIdx.x;
    if (i < n) cnt64[i] = 0ull;
}

// one packed atomic per edge; return value's count field = rank within dst bucket
__global__ void count_deg_rank_kernel(const int* __restrict__ dst, const float* __restrict__ ew,
                                      unsigned long long* __restrict__ cnt64,
                                      int* __restrict__ rank, int E) {
    int base = blockIdx.x * 1024 + threadIdx.x;    // block covers 1024 consecutive edges
    #pragma unroll
    for (int k = 0; k < 4; ++k) {
        int e = base + k * 256;
        if (e < E) {
            int d = dst[e];
            unsigned int q = __float2uint_rn(ew[e] * QSCALE);
            unsigned long long inc = (1ull << 40) | (unsigned long long)q;
            unsigned long long old = atomicAdd(&cnt64[d], inc);
            rank[e] = (int)(old >> 40);
        }
    }
}

// ---- hierarchical scan: cnt64 -> row_start (exclusive); dinv = rsqrt(1 + qsum/2^19) fused ----

constexpr int SCAN_T = 256;
constexpr int SCAN_E = 8;
constexpr int SCAN_ELEMS = SCAN_T * SCAN_E;      // 2048 elements per block

__global__ __launch_bounds__(SCAN_T) void block_sum_dinv_kernel(
        const unsigned long long* __restrict__ cnt64, float* __restrict__ dinv,
        int* __restrict__ bsum, int n) {
    __shared__ int sh[SCAN_T];
    int b = blockIdx.x, t = threadIdx.x;
    int base = b * SCAN_ELEMS;
    int lim = min(base + SCAN_ELEMS, n);
    int sum = 0;
    for (int i = base + t; i < lim; i += SCAN_T) {
        unsigned long long v = cnt64[i];
        sum += (int)(v >> 40);
        dinv[i] = rsqrtf(1.0f + (float)(v & MASK40) * (1.0f / QSCALE));
    }
    sh[t] = sum;
    __syncthreads();
    #pragma unroll
    for (int off = SCAN_T / 2; off > 0; off >>= 1) {
        if (t < off) sh[t] += sh[t + off];
        __syncthreads();
    }
    if (t == 0) bsum[b] = sh[0];
}

__global__ __launch_bounds__(256) void scan_bsums_kernel(const int* __restrict__ bsum,
                                                         int* __restrict__ boff, int P) {
    __shared__ int sh[256];
    int t = threadIdx.x;
    int v = (t < P) ? bsum[t] : 0;
    sh[t] = v;
    __syncthreads();
    #pragma unroll
    for (int off = 1; off < 256; off <<= 1) {
        int add = (t >= off) ? sh[t - off] : 0;
        __syncthreads();
        sh[t] += add;
        __syncthreads();
    }
    if (t < P) boff[t] = sh[t] - v;              // exclusive
}

__global__ __launch_bounds__(SCAN_T) void scan_within_kernel(
        const unsigned long long* __restrict__ cnt64, const int* __restrict__ boff,
        int* __restrict__ row_start, int n, int E) {
    __shared__ int sh[SCAN_T];
    int b = blockIdx.x, t = threadIdx.x;
    int base = b * SCAN_ELEMS + t * SCAN_E;
    int c[SCAN_E];
    #pragma unroll
    for (int k = 0; k < SCAN_E; ++k)
        c[k] = (base + k < n) ? (int)(cnt64[base + k] >> 40) : 0;
    int sum = 0;
    #pragma unroll
    for (int k = 0; k < SCAN_E; ++k) sum += c[k];
    sh[t] = sum;
    __syncthreads();
    #pragma unroll
    for (int off = 1; off < SCAN_T; off <<= 1) {   // Hillis-Steele inclusive
        int add = (t >= off) ? sh[t - off] : 0;
        __syncthreads();
        sh[t] += add;
        __syncthreads();
    }
    int run = boff[b] + sh[t] - sum;
    #pragma unroll
    for (int k = 0; k < SCAN_E; ++k) {
        int i = base + k;
        if (i < n) row_start[i] = run;
        run += c[k];
    }
    if (b == 0 && t == 0) row_start[n] = E;
}

// atomic-free scatter: pos = row_start[dst] + rank; payload = (src bits, norm)
__global__ void scatter_kernel(const int* __restrict__ src, const int* __restrict__ dst,
                               const float* __restrict__ ew, const int* __restrict__ rank,
                               const float* __restrict__ dinv, const int* __restrict__ row_start,
                               float2* __restrict__ epair, int E) {
    int base = blockIdx.x * 1024 + threadIdx.x;
    #pragma unroll
    for (int k = 0; k < 4; ++k) {
        int e = base + k * 256;
        if (e < E) {
            int s = src[e], d = dst[e];
            float w = dinv[s] * ew[e] * dinv[d];
            epair[row_start[d] + rank[e]] = make_float2(__int_as_float(s), w);
        }
    }
}

// ---------------- layer 1 fused: gather(D=2) + 2->16 matmul + relu ----------------
// 4-edge unrolled; remainder folded in via zero-weight pads (idx 0, w 0 -> no contribution)

__global__ void layer1_kernel(const float2* __restrict__ x2, const float* __restrict__ dinv,
                              const float2* __restrict__ epair, const int* __restrict__ row_start,
                              const float* __restrict__ W1, const float* __restrict__ b1,
                              float* __restrict__ h1, int n) {
    int i = blockIdx.x * blockDim.x + threadIdx.x;
    if (i >= n) return;
    float s = dinv[i];
    float2 xv = x2[i];
    float ax = xv.x * s * s, ay = xv.y * s * s;
    int beg = row_start[i], end = row_start[i + 1];
    const float2 zp = make_float2(0.0f, 0.0f);
    for (int e = beg; e < end; e += 4) {
        float2 p0 = epair[e];
        float2 p1 = (e + 1 < end) ? epair[e + 1] : zp;
        float2 p2 = (e + 2 < end) ? epair[e + 2] : zp;
        float2 p3 = (e + 3 < end) ? epair[e + 3] : zp;
        float2 v0 = x2[__float_as_int(p0.x)];
        float2 v1 = x2[__float_as_int(p1.x)];
        float2 v2 = x2[__float_as_int(p2.x)];
        float2 v3 = x2[__float_as_int(p3.x)];
        ax = fmaf(p0.y, v0.x, ax); ay = fmaf(p0.y, v0.y, ay);
        ax = fmaf(p1.y, v1.x, ax); ay = fmaf(p1.y, v1.y, ay);
        ax = fmaf(p2.y, v2.x, ax); ay = fmaf(p2.y, v2.y, ay);
        ax = fmaf(p3.y, v3.x, ax); ay = fmaf(p3.y, v3.y, ay);
    }
    float4* o = reinterpret_cast<float4*>(h1 + (size_t)i * 16);
    #pragma unroll
    for (int q = 0; q < 4; ++q) {
        float4 v;
        v.x = fmaxf(fmaf(ax, W1[4 * q + 0], fmaf(ay, W1[16 + 4 * q + 0], b1[4 * q + 0])), 0.f);
        v.y = fmaxf(fmaf(ax, W1[4 * q + 1], fmaf(ay, W1[16 + 4 * q + 1], b1[4 * q + 1])), 0.f);
        v.z = fmaxf(fmaf(ax, W1[4 * q + 2], fmaf(ay, W1[16 + 4 * q + 2], b1[4 * q + 2])), 0.f);
        v.w = fmaxf(fmaf(ax, W1[4 * q + 3], fmaf(ay, W1[16 + 4 * q + 3], b1[4 * q + 3])), 0.f);
        o[q] = v;
    }
}

// ---------------- gather: agg[i,d] = dinv[i]^2 h[i,d] + sum_e norm_e h[src_e,d] ----------------
// D lanes per node; 4-edge unrolled with zero-weight padding (no serial tail)

template<int D>
__global__ void gather_kernel(const float* __restrict__ h, const float* __restrict__ dinv,
                              const float2* __restrict__ epair, const int* __restrict__ row_start,
                              float* __restrict__ agg, int n) {
    int t = blockIdx.x * blockDim.x + threadIdx.x;
    int node = t / D, d = t % D;
    if (node >= n) return;
    float s = dinv[node];
    float acc = h[(size_t)node * D + d] * s * s;
    int beg = row_start[node], end = row_start[node + 1];
    const float2 zp = make_float2(0.0f, 0.0f);
    for (int e = beg; e < end; e += 4) {
        float2 p0 = epair[e];                      // broadcast across the D-lane group
        float2 p1 = (e + 1 < end) ? epair[e + 1] : zp;
        float2 p2 = (e + 2 < end) ? epair[e + 2] : zp;
        float2 p3 = (e + 3 < end) ? epair[e + 3] : zp;
        float v0 = h[(size_t)__float_as_int(p0.x) * D + d];   // 4 independent row reads
        float v1 = h[(size_t)__float_as_int(p1.x) * D + d];
        float v2 = h[(size_t)__float_as_int(p2.x) * D + d];
        float v3 = h[(size_t)__float_as_int(p3.x) * D + d];
        acc = fmaf(p0.y, v0, acc);
        acc = fmaf(p1.y, v1, acc);
        acc = fmaf(p2.y, v2, acc);
        acc = fmaf(p3.y, v3, acc);
    }
    agg[(size_t)node * D + d] = acc;
}

// ---------------- dense per-node matmul + ReLU ----------------

template<int DIN, int DOUT>
__global__ void linear_relu_kernel(const float* __restrict__ agg, const float* __restrict__ W,
                                   const float* __restrict__ b, float* __restrict__ out, int n) {
    int t = blockIdx.x * blockDim.x + threadIdx.x;
    if (t >= n * DOUT) return;
    int i = t / DOUT, f = t % DOUT;
    float acc = b[f];
    const float* ai = agg + (size_t)i * DIN;
    #pragma unroll
    for (int k = 0; k < DIN; ++k)
        acc = fmaf(ai[k], W[k * DOUT + f], acc);
    out[t] = fmaxf(acc, 0.0f);
}

// ---------------- layer 3 matmul + relu fused with head ----------------

__global__ void l3_head_kernel(const float* __restrict__ agg, const float* __restrict__ W3,
                               const float* __restrict__ b3, const float* __restrict__ Wl,
                               const float* __restrict__ bl, float* __restrict__ out, int n) {
    int i = blockIdx.x * blockDim.x + threadIdx.x;
    if (i >= n) return;
    float a[32];
    const float4* ap = reinterpret_cast<const float4*>(agg + (size_t)i * 32);
    #pragma unroll
    for (int q = 0; q < 8; ++q) {
        float4 v = ap[q];
        a[4 * q + 0] = v.x; a[4 * q + 1] = v.y; a[4 * q + 2] = v.z; a[4 * q + 3] = v.w;
    }
    float res = bl[0];
    for (int f = 0; f < 64; ++f) {                 // W3/b3/Wl lane-uniform -> scalar loads
        float acc = b3[f];
        #pragma unroll
        for (int k = 0; k < 32; ++k)
            acc = fmaf(a[k], W3[k * 64 + f], acc);
        res = fmaf(fmaxf(acc, 0.0f), Wl[f], res);
    }
    out[i] = res;
}

// ---------------- launch ----------------

static inline size_t align_up(size_t v, size_t a) { return (v + a - 1) & ~(a - 1); }

extern "C" void kernel_launch(void* const* d_in, const int* in_sizes, int n_in,
                              void* d_out, int out_size, void* d_ws, size_t ws_size,
                              hipStream_t stream) {
    const float* x  = (const float*)d_in[0];
    const int*   ei = (const int*)d_in[1];
    const float* ew = (const float*)d_in[2];
    const float* W1 = (const float*)d_in[3];
    const float* b1 = (const float*)d_in[4];
    const float* W2 = (const float*)d_in[5];
    const float* b2 = (const float*)d_in[6];
    const float* W3 = (const float*)d_in[7];
    const float* b3 = (const float*)d_in[8];
    const float* Wl = (const float*)d_in[9];
    const float* bl = (const float*)d_in[10];

    const int N = in_sizes[0] / 2;
    const int E = in_sizes[2];
    const int* src = ei;
    const int* dst = ei + E;

    char* ws = (char*)d_ws;
    size_t off = 0;
    unsigned long long* cnt64 = (unsigned long long*)(ws + off); off = align_up(off + (size_t)N * 8, 256);
    float*  dinv      = (float*)(ws + off);  off = align_up(off + (size_t)N * 4, 256);
    int*    row_start = (int*)(ws + off);    off = align_up(off + (size_t)(N + 1) * 4, 256);
    int*    rank      = (int*)(ws + off);    off = align_up(off + (size_t)E * 4, 256);
    int*    bsum      = (int*)(ws + off);    off = align_up(off + 256 * 4, 256);
    int*    boff      = (int*)(ws + off);    off = align_up(off + 256 * 4, 256);
    float2* epair     = (float2*)(ws + off); off = align_up(off + (size_t)E * 8, 256);
    float*  h1        = (float*)(ws + off);  off = align_up(off + (size_t)N * 16 * 4, 256);
    float*  h2        = (float*)(ws + off);  off = align_up(off + (size_t)N * 32 * 4, 256);
    float*  agg       = (float*)(ws + off);  off = align_up(off + (size_t)N * 32 * 4, 256);

    const int B = 256;
    const int gN = (N + B - 1) / B;
    const int gE4 = (E + 1023) / 1024;                 // 4 edges per thread
    const int P  = (N + SCAN_ELEMS - 1) / SCAN_ELEMS;  // 25 scan blocks for N=50000

    // CSR build (shared across all 3 layers) — exactly 1 atomic per edge total
    init_kernel<<<gN, B, 0, stream>>>(cnt64, N);
    count_deg_rank_kernel<<<gE4, B, 0, stream>>>(dst, ew, cnt64, rank, E);
    block_sum_dinv_kernel<<<P, SCAN_T, 0, stream>>>(cnt64, dinv, bsum, N);
    scan_bsums_kernel<<<1, 256, 0, stream>>>(bsum, boff, P);
    scan_within_kernel<<<P, SCAN_T, 0, stream>>>(cnt64, boff, row_start, N, E);
    scatter_kernel<<<gE4, B, 0, stream>>>(src, dst, ew, rank, dinv, row_start, epair, E);

    // layer 1: fused gather(D=2) + 2->16 matmul + relu
    layer1_kernel<<<gN, B, 0, stream>>>((const float2*)x, dinv, epair, row_start, W1, b1, h1, N);

    // layer 2: gather(D=16), 16->32 matmul + relu
    gather_kernel<16><<<(N * 16 + B - 1) / B, B, 0, stream>>>(h1, dinv, epair, row_start, agg, N);
    linear_relu_kernel<16, 32><<<(N * 32 + B - 1) / B, B, 0, stream>>>(agg, W2, b2, h2, N);

    // layer 3: gather(D=32), fused 32->64 matmul + relu + head
    gather_kernel<32><<<(N * 32 + B - 1) / B, B, 0, stream>>>(h2, dinv, epair, row_start, agg, N);
    l3_head_kernel<<<gN, B, 0, stream>>>(agg, W3, b3, Wl, bl, (float*)d_out, N);
}

// Round 7
// 157.580 us; speedup vs baseline: 20.5024x; 1.3847x over previous
//
#include <hip/hip_runtime.h>

// Fixed-point packing for the fused count+degree atomic:
//   low 40 bits  = sum of round(ew * 2^19)   (worst case 1.2M * 2^19 < 2^40)
//   high 24 bits = edge count
constexpr float QSCALE = 524288.0f;            // 2^19
constexpr unsigned long long MASK40 = (1ull << 40) - 1;

// ---------------- CSR build: 1 atomic per edge (measured floor ~21 G atomics/s) ----------------

__global__ void count_deg_rank_kernel(const int* __restrict__ dst, const float* __restrict__ ew,
                                      unsigned long long* __restrict__ cnt64,
                                      int* __restrict__ rank, int E) {
    int base = blockIdx.x * 1024 + threadIdx.x;
    #pragma unroll
    for (int k = 0; k < 4; ++k) {
        int e = base + k * 256;
        if (e < E) {
            int d = dst[e];
            unsigned int q = __float2uint_rn(ew[e] * QSCALE);
            unsigned long long inc = (1ull << 40) | (unsigned long long)q;
            unsigned long long old = atomicAdd(&cnt64[d], inc);
            rank[e] = (int)(old >> 40);
        }
    }
}

// ---- hierarchical scan: cnt64 -> row_start (exclusive); dinv = rsqrt(1 + qsum/2^19) fused ----

constexpr int SCAN_T = 256;
constexpr int SCAN_E = 8;
constexpr int SCAN_ELEMS = SCAN_T * SCAN_E;      // 2048 per block

__global__ __launch_bounds__(SCAN_T) void block_sum_dinv_kernel(
        const unsigned long long* __restrict__ cnt64, float* __restrict__ dinv,
        int* __restrict__ bsum, int n) {
    __shared__ int sh[SCAN_T];
    int b = blockIdx.x, t = threadIdx.x;
    int base = b * SCAN_ELEMS;
    int lim = min(base + SCAN_ELEMS, n);
    int sum = 0;
    for (int i = base + t; i < lim; i += SCAN_T) {
        unsigned long long v = cnt64[i];
        sum += (int)(v >> 40);
        dinv[i] = rsqrtf(1.0f + (float)(v & MASK40) * (1.0f / QSCALE));
    }
    sh[t] = sum;
    __syncthreads();
    #pragma unroll
    for (int off = SCAN_T / 2; off > 0; off >>= 1) {
        if (t < off) sh[t] += sh[t + off];
        __syncthreads();
    }
    if (t == 0) bsum[b] = sh[0];
}

__global__ __launch_bounds__(256) void scan_bsums_kernel(const int* __restrict__ bsum,
                                                         int* __restrict__ boff, int P) {
    __shared__ int sh[256];
    int t = threadIdx.x;
    int v = (t < P) ? bsum[t] : 0;
    sh[t] = v;
    __syncthreads();
    #pragma unroll
    for (int off = 1; off < 256; off <<= 1) {
        int add = (t >= off) ? sh[t - off] : 0;
        __syncthreads();
        sh[t] += add;
        __syncthreads();
    }
    if (t < P) boff[t] = sh[t] - v;              // exclusive
}

__global__ __launch_bounds__(SCAN_T) void scan_within_kernel(
        const unsigned long long* __restrict__ cnt64, const int* __restrict__ boff,
        int* __restrict__ row_start, int n, int E) {
    __shared__ int sh[SCAN_T];
    int b = blockIdx.x, t = threadIdx.x;
    int base = b * SCAN_ELEMS + t * SCAN_E;
    int c[SCAN_E];
    #pragma unroll
    for (int k = 0; k < SCAN_E; ++k)
        c[k] = (base + k < n) ? (int)(cnt64[base + k] >> 40) : 0;
    int sum = 0;
    #pragma unroll
    for (int k = 0; k < SCAN_E; ++k) sum += c[k];
    sh[t] = sum;
    __syncthreads();
    #pragma unroll
    for (int off = 1; off < SCAN_T; off <<= 1) {   // Hillis-Steele inclusive
        int add = (t >= off) ? sh[t - off] : 0;
        __syncthreads();
        sh[t] += add;
        __syncthreads();
    }
    int run = boff[b] + sh[t] - sum;
    #pragma unroll
    for (int k = 0; k < SCAN_E; ++k) {
        int i = base + k;
        if (i < n) row_start[i] = run;
        run += c[k];
    }
    if (b == 0 && t == 0) row_start[n] = E;
}

// atomic-free scatter: pos = row_start[dst] + rank; payload = (src bits, norm)
__global__ void scatter_kernel(const int* __restrict__ src, const int* __restrict__ dst,
                               const float* __restrict__ ew, const int* __restrict__ rank,
                               const float* __restrict__ dinv, const int* __restrict__ row_start,
                               float2* __restrict__ epair, int E) {
    int base = blockIdx.x * 2048 + threadIdx.x;
    #pragma unroll
    for (int k = 0; k < 8; ++k) {
        int e = base + k * 256;
        if (e < E) {
            int s = src[e], d = dst[e];
            float w = dinv[s] * ew[e] * dinv[d];
            epair[row_start[d] + rank[e]] = make_float2(__int_as_float(s), w);
        }
    }
}

// ---------------- layer 1 fused: gather(D=2) + 2->16 matmul + relu (unroll 8) ----------------

__global__ void layer1_kernel(const float2* __restrict__ x2, const float* __restrict__ dinv,
                              const float2* __restrict__ epair, const int* __restrict__ row_start,
                              const float* __restrict__ W1, const float* __restrict__ b1,
                              float* __restrict__ h1, int n) {
    int i = blockIdx.x * blockDim.x + threadIdx.x;
    if (i >= n) return;
    float s = dinv[i];
    float2 xv = x2[i];
    float ax = xv.x * s * s, ay = xv.y * s * s;
    int beg = row_start[i], end = row_start[i + 1];
    for (int e = beg; e < end; e += 8) {
        #pragma unroll
        for (int k = 0; k < 8; ++k) {
            float2 p = epair[min(e + k, end - 1)];        // always-valid load
            float w = (e + k < end) ? p.y : 0.0f;         // zero-weight pad
            float2 v = x2[__float_as_int(p.x)];
            ax = fmaf(w, v.x, ax);
            ay = fmaf(w, v.y, ay);
        }
    }
    float4* o = reinterpret_cast<float4*>(h1 + (size_t)i * 16);
    #pragma unroll
    for (int q = 0; q < 4; ++q) {
        float4 v;
        v.x = fmaxf(fmaf(ax, W1[4 * q + 0], fmaf(ay, W1[16 + 4 * q + 0], b1[4 * q + 0])), 0.f);
        v.y = fmaxf(fmaf(ax, W1[4 * q + 1], fmaf(ay, W1[16 + 4 * q + 1], b1[4 * q + 1])), 0.f);
        v.z = fmaxf(fmaf(ax, W1[4 * q + 2], fmaf(ay, W1[16 + 4 * q + 2], b1[4 * q + 2])), 0.f);
        v.w = fmaxf(fmaf(ax, W1[4 * q + 3], fmaf(ay, W1[16 + 4 * q + 3], b1[4 * q + 3])), 0.f);
        o[q] = v;
    }
}

// ---------------- layer 2 fused: gather(D=16, float4 lanes) + 16->32 matmul + relu ----------------
// 4 lanes per node x float4; 64 nodes/block; agg staged in LDS (stride 20 = 2-way free conflict)

__global__ __launch_bounds__(256) void gather16_linear_kernel(
        const float4* __restrict__ h4, const float* __restrict__ dinv,
        const float2* __restrict__ epair, const int* __restrict__ row_start,
        const float* __restrict__ W2, const float* __restrict__ b2,
        float4* __restrict__ h2_4, int n) {
    __shared__ float sh_agg[64 * 20];
    __shared__ float sh_W2[16 * 32];
    int t = threadIdx.x;
    {   // preload W2 (512 floats)
        float2 w = reinterpret_cast<const float2*>(W2)[t];
        sh_W2[2 * t] = w.x; sh_W2[2 * t + 1] = w.y;
    }
    int nl = t >> 2, q = t & 3;
    int node = blockIdx.x * 64 + nl;
    if (node < n) {
        float s = dinv[node];
        float ss = s * s;
        float4 acc = h4[(size_t)node * 4 + q];
        acc.x *= ss; acc.y *= ss; acc.z *= ss; acc.w *= ss;
        int beg = row_start[node], end = row_start[node + 1];
        for (int e = beg; e < end; e += 4) {
            float2 p0 = epair[e];
            float2 p1 = epair[min(e + 1, end - 1)];
            float2 p2 = epair[min(e + 2, end - 1)];
            float2 p3 = epair[min(e + 3, end - 1)];
            float w1 = (e + 1 < end) ? p1.y : 0.f;
            float w2 = (e + 2 < end) ? p2.y : 0.f;
            float w3 = (e + 3 < end) ? p3.y : 0.f;
            float4 v0 = h4[(size_t)__float_as_int(p0.x) * 4 + q];
            float4 v1 = h4[(size_t)__float_as_int(p1.x) * 4 + q];
            float4 v2 = h4[(size_t)__float_as_int(p2.x) * 4 + q];
            float4 v3 = h4[(size_t)__float_as_int(p3.x) * 4 + q];
            acc.x = fmaf(p0.y, v0.x, acc.x); acc.y = fmaf(p0.y, v0.y, acc.y);
            acc.z = fmaf(p0.y, v0.z, acc.z); acc.w = fmaf(p0.y, v0.w, acc.w);
            acc.x = fmaf(w1, v1.x, acc.x);  acc.y = fmaf(w1, v1.y, acc.y);
            acc.z = fmaf(w1, v1.z, acc.z);  acc.w = fmaf(w1, v1.w, acc.w);
            acc.x = fmaf(w2, v2.x, acc.x);  acc.y = fmaf(w2, v2.y, acc.y);
            acc.z = fmaf(w2, v2.z, acc.z);  acc.w = fmaf(w2, v2.w, acc.w);
            acc.x = fmaf(w3, v3.x, acc.x);  acc.y = fmaf(w3, v3.y, acc.y);
            acc.z = fmaf(w3, v3.z, acc.z);  acc.w = fmaf(w3, v3.w, acc.w);
        }
        *reinterpret_cast<float4*>(&sh_agg[nl * 20 + q * 4]) = acc;
    }
    __syncthreads();
    // phase 2: 16->32 matmul + relu; thread -> (node, 8 outputs)
    int fg = t & 3;
    if (node < n) {
        const float* a = &sh_agg[nl * 20];
        float4 acc0 = reinterpret_cast<const float4*>(b2)[fg * 2];
        float4 acc1 = reinterpret_cast<const float4*>(b2)[fg * 2 + 1];
        #pragma unroll
        for (int k = 0; k < 16; ++k) {
            float ak = a[k];
            float4 w0 = *reinterpret_cast<const float4*>(&sh_W2[k * 32 + fg * 8]);
            float4 w1 = *reinterpret_cast<const float4*>(&sh_W2[k * 32 + fg * 8 + 4]);
            acc0.x = fmaf(ak, w0.x, acc0.x); acc0.y = fmaf(ak, w0.y, acc0.y);
            acc0.z = fmaf(ak, w0.z, acc0.z); acc0.w = fmaf(ak, w0.w, acc0.w);
            acc1.x = fmaf(ak, w1.x, acc1.x); acc1.y = fmaf(ak, w1.y, acc1.y);
            acc1.z = fmaf(ak, w1.z, acc1.z); acc1.w = fmaf(ak, w1.w, acc1.w);
        }
        acc0.x = fmaxf(acc0.x, 0.f); acc0.y = fmaxf(acc0.y, 0.f);
        acc0.z = fmaxf(acc0.z, 0.f); acc0.w = fmaxf(acc0.w, 0.f);
        acc1.x = fmaxf(acc1.x, 0.f); acc1.y = fmaxf(acc1.y, 0.f);
        acc1.z = fmaxf(acc1.z, 0.f); acc1.w = fmaxf(acc1.w, 0.f);
        h2_4[(size_t)node * 8 + fg * 2]     = acc0;
        h2_4[(size_t)node * 8 + fg * 2 + 1] = acc1;
    }
}

// ---------------- layer 3 fused: gather(D=32, float4 lanes) + relu(aggW3+b3)@Wl+bl ----------------
// 8 lanes per node x float4; 32 nodes/block; W3 transposed in LDS; f = g + 8*j (bank-clean)

__global__ __launch_bounds__(256) void gather32_head_kernel(
        const float4* __restrict__ h4, const float* __restrict__ dinv,
        const float2* __restrict__ epair, const int* __restrict__ row_start,
        const float* __restrict__ W3, const float* __restrict__ b3,
        const float* __restrict__ Wl, const float* __restrict__ bl,
        float* __restrict__ out, int n) {
    __shared__ float sh_agg[32 * 36];
    __shared__ float sh_W3T[64 * 36];                  // row f: W3[0..31][f]
    int t = threadIdx.x;
    #pragma unroll
    for (int i = 0; i < 8; ++i) {                      // preload W3 transposed (2048 floats)
        int idx = t + i * 256;
        sh_W3T[(idx & 63) * 36 + (idx >> 6)] = W3[idx];
    }
    int nl = t >> 3, q = t & 7;
    int node = blockIdx.x * 32 + nl;
    if (node < n) {
        float s = dinv[node];
        float ss = s * s;
        float4 acc = h4[(size_t)node * 8 + q];
        acc.x *= ss; acc.y *= ss; acc.z *= ss; acc.w *= ss;
        int beg = row_start[node], end = row_start[node + 1];
        for (int e = beg; e < end; e += 4) {
            float2 p0 = epair[e];
            float2 p1 = epair[min(e + 1, end - 1)];
            float2 p2 = epair[min(e + 2, end - 1)];
            float2 p3 = epair[min(e + 3, end - 1)];
            float w1 = (e + 1 < end) ? p1.y : 0.f;
            float w2 = (e + 2 < end) ? p2.y : 0.f;
            float w3 = (e + 3 < end) ? p3.y : 0.f;
            float4 v0 = h4[(size_t)__float_as_int(p0.x) * 8 + q];
            float4 v1 = h4[(size_t)__float_as_int(p1.x) * 8 + q];
            float4 v2 = h4[(size_t)__float_as_int(p2.x) * 8 + q];
            float4 v3 = h4[(size_t)__float_as_int(p3.x) * 8 + q];
            acc.x = fmaf(p0.y, v0.x, acc.x); acc.y = fmaf(p0.y, v0.y, acc.y);
            acc.z = fmaf(p0.y, v0.z, acc.z); acc.w = fmaf(p0.y, v0.w, acc.w);
            acc.x = fmaf(w1, v1.x, acc.x);  acc.y = fmaf(w1, v1.y, acc.y);
            acc.z = fmaf(w1, v1.z, acc.z);  acc.w = fmaf(w1, v1.w, acc.w);
            acc.x = fmaf(w2, v2.x, acc.x);  acc.y = fmaf(w2, v2.y, acc.y);
            acc.z = fmaf(w2, v2.z, acc.z);  acc.w = fmaf(w2, v2.w, acc.w);
            acc.x = fmaf(w3, v3.x, acc.x);  acc.y = fmaf(w3, v3.y, acc.y);
            acc.z = fmaf(w3, v3.z, acc.z);  acc.w = fmaf(w3, v3.w, acc.w);
        }
        *reinterpret_cast<float4*>(&sh_agg[nl * 36 + q * 4]) = acc;
    }
    __syncthreads();
    // phase 2: per node, 8 lanes x 8 outputs each; reduce across lanes
    int g = t & 7;
    float res = 0.0f;
    if (node < n) {
        float a[32];
        #pragma unroll
        for (int c = 0; c < 8; ++c) {
            float4 v = *reinterpret_cast<const float4*>(&sh_agg[nl * 36 + c * 4]);
            a[c * 4] = v.x; a[c * 4 + 1] = v.y; a[c * 4 + 2] = v.z; a[c * 4 + 3] = v.w;
        }
        #pragma unroll
        for (int j = 0; j < 8; ++j) {
            int f = g + 8 * j;
            float acc = b3[f];
            const float* wr = &sh_W3T[f * 36];
            #pragma unroll
            for (int c = 0; c < 8; ++c) {
                float4 w = *reinterpret_cast<const float4*>(&wr[c * 4]);
                acc = fmaf(a[c * 4], w.x, acc);
                acc = fmaf(a[c * 4 + 1], w.y, acc);
                acc = fmaf(a[c * 4 + 2], w.z, acc);
                acc = fmaf(a[c * 4 + 3], w.w, acc);
            }
            res = fmaf(fmaxf(acc, 0.0f), Wl[f], res);
        }
    }
    res += __shfl_xor(res, 1);
    res += __shfl_xor(res, 2);
    res += __shfl_xor(res, 4);
    if (node < n && g == 0) out[node] = res + bl[0];
}

// ---------------- launch ----------------

static inline size_t align_up(size_t v, size_t a) { return (v + a - 1) & ~(a - 1); }

extern "C" void kernel_launch(void* const* d_in, const int* in_sizes, int n_in,
                              void* d_out, int out_size, void* d_ws, size_t ws_size,
                              hipStream_t stream) {
    const float* x  = (const float*)d_in[0];
    const int*   ei = (const int*)d_in[1];
    const float* ew = (const float*)d_in[2];
    const float* W1 = (const float*)d_in[3];
    const float* b1 = (const float*)d_in[4];
    const float* W2 = (const float*)d_in[5];
    const float* b2 = (const float*)d_in[6];
    const float* W3 = (const float*)d_in[7];
    const float* b3 = (const float*)d_in[8];
    const float* Wl = (const float*)d_in[9];
    const float* bl = (const float*)d_in[10];

    const int N = in_sizes[0] / 2;
    const int E = in_sizes[2];
    const int* src = ei;
    const int* dst = ei + E;

    char* ws = (char*)d_ws;
    size_t off = 0;
    unsigned long long* cnt64 = (unsigned long long*)(ws + off); off = align_up(off + (size_t)N * 8, 256);
    float*  dinv      = (float*)(ws + off);  off = align_up(off + (size_t)N * 4, 256);
    int*    row_start = (int*)(ws + off);    off = align_up(off + (size_t)(N + 1) * 4, 256);
    int*    rank      = (int*)(ws + off);    off = align_up(off + (size_t)E * 4, 256);
    int*    bsum      = (int*)(ws + off);    off = align_up(off + 256 * 4, 256);
    int*    boff      = (int*)(ws + off);    off = align_up(off + 256 * 4, 256);
    float2* epair     = (float2*)(ws + off); off = align_up(off + (size_t)E * 8, 256);
    float*  h1        = (float*)(ws + off);  off = align_up(off + (size_t)N * 16 * 4, 256);
    float*  h2        = (float*)(ws + off);  off = align_up(off + (size_t)N * 32 * 4, 256);

    const int B = 256;
    const int gN  = (N + B - 1) / B;
    const int gE4 = (E + 1023) / 1024;
    const int gE8 = (E + 2047) / 2048;
    const int P   = (N + SCAN_ELEMS - 1) / SCAN_ELEMS;

    // CSR build (shared across all 3 layers) — exactly 1 atomic per edge total
    hipMemsetAsync(cnt64, 0, (size_t)N * 8, stream);
    count_deg_rank_kernel<<<gE4, B, 0, stream>>>(dst, ew, cnt64, rank, E);
    block_sum_dinv_kernel<<<P, SCAN_T, 0, stream>>>(cnt64, dinv, bsum, N);
    scan_bsums_kernel<<<1, 256, 0, stream>>>(bsum, boff, P);
    scan_within_kernel<<<P, SCAN_T, 0, stream>>>(cnt64, boff, row_start, N, E);
    scatter_kernel<<<gE8, B, 0, stream>>>(src, dst, ew, rank, dinv, row_start, epair, E);

    // layer 1: gather(D=2) + 2->16 matmul + relu
    layer1_kernel<<<gN, B, 0, stream>>>((const float2*)x, dinv, epair, row_start, W1, b1, h1, N);

    // layer 2: fused gather(16) + 16->32 matmul + relu
    gather16_linear_kernel<<<(N + 63) / 64, 256, 0, stream>>>(
        (const float4*)h1, dinv, epair, row_start, W2, b2, (float4*)h2, N);

    // layer 3: fused gather(32) + relu(.@W3+b3) @ Wl + bl
    gather32_head_kernel<<<(N + 31) / 32, 256, 0, stream>>>(
        (const float4*)h2, dinv, epair, row_start, W3, b3, Wl, bl, (float*)d_out, N);
}